// Round 2
// baseline (352.825 us; speedup 1.0000x reference)
//
#include <hip/hip_runtime.h>
#include <cstdint>
#include <cmath>

#define DEV __device__ __forceinline__

constexpr int SEL = 20;
constexpr int NSTEP2 = 10, NSTEP3 = 22, NSTEPS = 32;
constexpr int L2 = SEL + 1;   // 21 bits, group2
constexpr int L3 = SEL;       // 20 bits, group3
constexpr int H = 4;
constexpr int P = 8;          // Chebyshev probes

// ---- ws layout (float indices) ----
constexpr int OFF_T      = 0;                               // T[2][22][P] = 352
constexpr int OFF_SUMS   = OFF_T + 2 * 22 * P;              // 352
constexpr int SUMS_STRIDE = 96;                             // [0]=Se [1]=Sw [2..5]=Sws [6..9]=Swh [10+h*21+d]=GW1
constexpr int OFF_PCHAIN = OFF_SUMS + NSTEPS * SUMS_STRIDE; // 3424 ; pchain[33]
constexpr int OFF_KEYB   = OFF_PCHAIN + 40;                 // keybase[32][4]
constexpr int OFF_CT     = OFF_KEYB + 128;                  // int c_t[32]
constexpr int OFF_CB     = OFF_CT + 32;                     // uint chunkbits[32]
constexpr int OFF_NEED   = OFF_CB + 32;                     // uint neededmask[2]
constexpr int WS_FLOATS  = OFF_NEED + 8;

__constant__ float CHEB_P[P] = {0.9903926402f, 0.9157348062f, 0.7777851165f, 0.5975451610f,
                                0.4024548390f, 0.2222148835f, 0.0842651938f, 0.0096073598f};
__constant__ float CHEB_W[P] = {0.1950903220f, -0.5555702330f, 0.8314696123f, -0.9807852804f,
                                0.9807852804f, -0.8314696123f, 0.5555702330f, -0.1950903220f};

struct Binom { unsigned v[22][22]; };
constexpr Binom make_binom() {
  Binom b{};
  for (int n = 0; n < 22; n++) {
    b.v[n][0] = 1;
    for (int k = 1; k < 22; k++)
      b.v[n][k] = (k > n) ? 0u : (k == n ? 1u : b.v[n - 1][k - 1] + b.v[n - 1][k]);
  }
  return b;
}
__device__ constexpr Binom BN = make_binom();

DEV float fast_tanh(float x) {
  float e = exp2f(x * 2.8853900817779268f);  // e^(2x)
  return 1.0f - 2.0f * __builtin_amdgcn_rcpf(e + 1.0f);
}
DEV float fast_exp(float x) { return exp2f(x * 1.4426950408889634f); }

// =================== Kernel Z: init / decode chunks ===================
__global__ void kz(const float* p0, const float* sel,
                   const float* W1_2, const float* b1_2,
                   const float* W1_3, const float* b1_3, float* ws) {
  int t = threadIdx.x;
  for (int i = t; i < WS_FLOATS; i += blockDim.x) ws[i] = 0.0f;
  __syncthreads();
  if (t < NSTEPS) {
    int g = (t < NSTEP2) ? 0 : 1;
    int L = g ? L3 : L2;
    const float* sbase = sel + (g ? (NSTEP2 * L2 + (t - NSTEP2) * L3) : t * L2);
    unsigned cb = 0; int c = 0;
    for (int d = 0; d < L; d++)
      if (sbase[d] > 0.5f) { cb |= 1u << d; c++; }
    ((int*)ws)[OFF_CT + t] = c;
    ((unsigned*)ws)[OFF_CB + t] = cb;
    atomicOr(&((unsigned*)ws)[OFF_NEED + g], 1u << c);
    const float* W1 = g ? W1_3 : W1_2;
    const float* b1 = g ? b1_3 : b1_2;
    for (int h = 0; h < H; h++) {
      float s = b1[h];
      for (int d = 0; d < L; d++)
        if ((cb >> d) & 1) s += W1[h * (L + 1) + 1 + d];
      ws[OFF_KEYB + t * 4 + h] = s;
    }
    if (t == 0) ws[OFF_PCHAIN] = p0[0];
  }
}

// =================== Kernel A: tabulate T[g][c][j] at Chebyshev nodes ===================
constexpr int A_BLOCKS2 = 256, A_BLOCKS3 = 128; // 8192 combos/block
constexpr int A_CPT = 8;

__global__ __launch_bounds__(1024) void ka(
    const float* W1_2, const float* b1_2, const float* W2_2, const float* b2_2,
    const float* W1_3, const float* b1_3, const float* W2_3, const float* b2_3,
    float* ws) {
  __shared__ unsigned sBN[22][22];
  __shared__ float4 tab0[128], tab1[128], tab2[128];
  __shared__ float sT[22][P];
  int g = (blockIdx.x < A_BLOCKS2) ? 0 : 1;
  int L = g ? L3 : L2;
  unsigned rank0 = (g ? (blockIdx.x - A_BLOCKS2) : blockIdx.x) * (1024u * A_CPT);
  const float* W1 = g ? W1_3 : W1_2;  const float* b1 = g ? b1_3 : b1_2;
  const float* W2 = g ? W2_3 : W2_2;  float b2s = (g ? b2_3 : b2_2)[0];
  unsigned need = ((const unsigned*)ws)[OFF_NEED + g];
  int tx = threadIdx.x;
  for (int i = tx; i < 484; i += 1024) { int n = i / 22, k = i % 22; sBN[n][k] = BN.v[n][k]; }
  for (int i = tx; i < 384; i += 1024) {
    int which = i >> 7, e = i & 127;
    int lo = which * 7; int nb = (which < 2) ? 7 : (L - 14);
    float4 v; float* vp = (float*)&v;
    for (int h = 0; h < 4; h++) {
      float s = (which == 0) ? b1[h] : 0.0f;
      for (int j = 0; j < nb; j++)
        if ((e >> j) & 1) s += W1[h * (L + 1) + 1 + lo + j];
      vp[h] = s;
    }
    if (which == 0) tab0[e] = v; else if (which == 1) tab1[e] = v; else tab2[e] = v;
  }
  for (int i = tx; i < 22 * P; i += 1024) ((float*)sT)[i] = 0.0f;
  __syncthreads();
  float a0 = W1[0], a1 = W1[L + 1], a2 = W1[2 * (L + 1)], a3 = W1[3 * (L + 1)];
  float w0 = W2[0], w1 = W2[1], w2 = W2[2], w3 = W2[3];

  unsigned R = rank0 + (unsigned)tx * A_CPT;
  int c = 0;
  while (c <= L && R >= sBN[L][c]) { R -= sBN[L][c]; c++; }
  unsigned combo = 0; bool valid = false;
  float acc[P];
#pragma unroll
  for (int j = 0; j < P; j++) acc[j] = 0.0f;
  int acc_c = -1;
  for (int k = 0; k < A_CPT; k++) {
    if (c > L) break;
    bool needc = (need >> c) & 1;
    if (needc) {
      if (!valid) {
        combo = 0; unsigned r = R; int kk = c;
        for (int bb = L - 1; bb >= 0 && kk > 0; bb--) {
          unsigned cnt = sBN[bb][kk];
          if (r >= cnt) { combo |= 1u << bb; r -= cnt; kk--; }
        }
        valid = true;
      }
      if (acc_c != c) {
        if (acc_c >= 0) {
#pragma unroll
          for (int j = 0; j < P; j++)
            if (acc[j] != 0.0f) atomicAdd(&sT[acc_c][j], acc[j]);
#pragma unroll
          for (int j = 0; j < P; j++) acc[j] = 0.0f;
        }
        acc_c = c;
      }
      float4 v0 = tab0[combo & 127], v1 = tab1[(combo >> 7) & 127], v2 = tab2[(combo >> 14) & 127];
      float base0 = v0.x + v1.x + v2.x, base1 = v0.y + v1.y + v2.y;
      float base2 = v0.z + v1.z + v2.z, base3 = v0.w + v1.w + v2.w;
#pragma unroll
      for (int j = 0; j < P; j++) {
        float p = CHEB_P[j];
        float t0 = fast_tanh(base0 + p * a0);
        float t1 = fast_tanh(base1 + p * a1);
        float t2 = fast_tanh(base2 + p * a2);
        float t3 = fast_tanh(base3 + p * a3);
        float out = b2s + w0 * t0 + w1 * t1 + w2 * t2 + w3 * t3;
        acc[j] += fast_exp(out);
      }
    }
    R++;
    if (R >= sBN[L][c]) { c++; R = 0; valid = false; }
    else if (valid) {
      unsigned u = combo & (~combo + 1u);
      unsigned v = combo + u;
      combo = v | ((combo ^ v) >> (1 + __ffs(u)));
    }
  }
  // final flush (reconverged): wave-uniform fast path
  int first_c = __shfl(acc_c, 0);
  bool uni = __all(acc_c == first_c);
  if (uni && first_c >= 0) {
#pragma unroll
    for (int j = 0; j < P; j++) {
      float v = acc[j];
      for (int m = 1; m < 64; m <<= 1) v += __shfl_xor(v, m);
      if ((tx & 63) == 0 && v != 0.0f) atomicAdd(&sT[first_c][j], v);
    }
  } else if (acc_c >= 0) {
#pragma unroll
    for (int j = 0; j < P; j++)
      if (acc[j] != 0.0f) atomicAdd(&sT[acc_c][j], acc[j]);
  }
  __syncthreads();
  for (int i = tx; i < 22 * P; i += 1024) {
    float v = ((float*)sT)[i];
    if (v != 0.0f) atomicAdd(&ws[OFF_T + g * 22 * P + i], v);
  }
}

// =================== Kernel B: sequential prob chain via Chebyshev interp ===================
__global__ void kb(const float* p0in,
                   const float* W1_2, const float* b1_2, const float* W2_2, const float* b2_2,
                   const float* W1_3, const float* b1_3, const float* W2_3, const float* b2_3,
                   float* ws, float* out) {
  if (threadIdx.x != 0) return;
  float p = p0in[0];
  out[0] = p;
  ws[OFF_PCHAIN] = p;
  for (int tt = 0; tt < NSTEPS; tt++) {
    int g = (tt < NSTEP2) ? 0 : 1;
    int L = g ? L3 : L2;
    const float* W1 = g ? W1_3 : W1_2;
    const float* W2 = g ? W2_3 : W2_2;
    float b2s = (g ? b2_3 : b2_2)[0];
    int c = ((const int*)ws)[OFF_CT + tt];
    float outk = b2s;
    for (int h = 0; h < H; h++) {
      float hk = fast_tanh(ws[OFF_KEYB + tt * 4 + h] + p * W1[h * (L + 1)]);
      outk += W2[h] * hk;
    }
    const float* T = &ws[OFF_T + g * 22 * P + c * P];
    float num = 0.0f, den = 0.0f, Sehit = 0.0f;
    bool hit = false;
#pragma unroll
    for (int j = 0; j < P; j++) {
      float d = p - CHEB_P[j];
      if (fabsf(d) < 1e-8f) { hit = true; Sehit = T[j]; }
      else { float q = CHEB_W[j] / d; num += q * T[j]; den += q; }
    }
    float Se = hit ? Sehit : (num / den);
    p = fast_exp(outk) / Se;
    ws[OFF_PCHAIN + 1 + tt] = p;
    out[1 + tt] = p;
  }
}

// =================== Kernel C: exact 94-sum reductions, all steps in parallel ===================
constexpr int C_SUB2 = 32;  // 2^15 threads per group2 step
constexpr int C_SUB3 = 16;  // 2^14 threads per group3 step
constexpr int C_BLOCKS = NSTEP2 * C_SUB2 + NSTEP3 * C_SUB3; // 672

__global__ __launch_bounds__(1024) void kc(
    const float* W1_2, const float* b1_2, const float* W2_2, const float* b2_2,
    const float* W1_3, const float* b1_3, const float* W2_3, const float* b2_3,
    float* ws) {
  __shared__ float4 tab0[128], tab1[128], tab2[128];
  __shared__ float sS[SUMS_STRIDE];
  int b = blockIdx.x;
  int t, sub, L, Tlg, g;
  if (b < NSTEP2 * C_SUB2) { t = b / C_SUB2; sub = b % C_SUB2; g = 0; L = L2; Tlg = 15; }
  else { int bb = b - NSTEP2 * C_SUB2; t = NSTEP2 + bb / C_SUB3; sub = bb % C_SUB3; g = 1; L = L3; Tlg = 14; }
  const float* W1 = g ? W1_3 : W1_2;  const float* b1 = g ? b1_3 : b1_2;
  const float* W2 = g ? W2_3 : W2_2;  float b2s = (g ? b2_3 : b2_2)[0];
  int tx = threadIdx.x;
  for (int i = tx; i < 384; i += 1024) {
    int which = i >> 7, e = i & 127;
    int lo = which * 7; int nb = (which < 2) ? 7 : (L - 14);
    float4 v; float* vp = (float*)&v;
    for (int h = 0; h < 4; h++) {
      float s = (which == 0) ? b1[h] : 0.0f;
      for (int j = 0; j < nb; j++)
        if ((e >> j) & 1) s += W1[h * (L + 1) + 1 + lo + j];
      vp[h] = s;
    }
    if (which == 0) tab0[e] = v; else if (which == 1) tab1[e] = v; else tab2[e] = v;
  }
  for (int i = tx; i < SUMS_STRIDE; i += 1024) sS[i] = 0.0f;
  __syncthreads();
  int c_t = ((const int*)ws)[OFF_CT + t];
  float p = ws[OFF_PCHAIN + t];
  float a0 = W1[0], a1 = W1[L + 1], a2 = W1[2 * (L + 1)], a3 = W1[3 * (L + 1)];
  float w0 = W2[0], w1 = W2[1], w2 = W2[2], w3 = W2[3];
  unsigned tid_s = ((unsigned)sub << 10) | (unsigned)tx;
  int c_low = __popc(tid_s);
  int cmin = c_low, cmax = c_low;
  for (int m = 1; m < 64; m <<= 1) {
    int o = __shfl_xor(cmin, m); cmin = min(cmin, o);
    o = __shfl_xor(cmax, m);     cmax = max(cmax, o);
  }
  float acc_e = 0, acc_w = 0, acc_ws[4] = {0, 0, 0, 0}, acc_wh[4] = {0, 0, 0, 0};
  float acc_hi[6][4];
#pragma unroll
  for (int k = 0; k < 6; k++)
#pragma unroll
    for (int h = 0; h < 4; h++) acc_hi[k][h] = 0.0f;

  for (unsigned i = 0; i < 64; i++) {
    int pci = __popc(i);
    if (c_t - pci < cmin || c_t - pci > cmax) continue; // wave-uniform skip
    if (c_low + pci == c_t) {
      unsigned n = (i << Tlg) | tid_s;
      float4 v0 = tab0[n & 127], v1 = tab1[(n >> 7) & 127], v2 = tab2[(n >> 14) & 127];
      float t0 = fast_tanh(v0.x + v1.x + v2.x + p * a0);
      float t1 = fast_tanh(v0.y + v1.y + v2.y + p * a1);
      float t2 = fast_tanh(v0.z + v1.z + v2.z + p * a2);
      float t3 = fast_tanh(v0.w + v1.w + v2.w + p * a3);
      float out = b2s + w0 * t0 + w1 * t1 + w2 * t2 + w3 * t3;
      float e = fast_exp(out);
      float s0 = (1.0f - t0 * t0) * w0, s1 = (1.0f - t1 * t1) * w1;
      float s2 = (1.0f - t2 * t2) * w2, s3 = (1.0f - t3 * t3) * w3;
      float q0 = out * s0, q1 = out * s1, q2 = out * s2, q3 = out * s3;
      acc_e += e; acc_w += out;
      acc_ws[0] += q0; acc_ws[1] += q1; acc_ws[2] += q2; acc_ws[3] += q3;
      acc_wh[0] += out * t0; acc_wh[1] += out * t1; acc_wh[2] += out * t2; acc_wh[3] += out * t3;
#pragma unroll
      for (int k = 0; k < 6; k++)
        if ((i >> k) & 1) { acc_hi[k][0] += q0; acc_hi[k][1] += q1; acc_hi[k][2] += q2; acc_hi[k][3] += q3; }
    }
  }
  // --- epilogue: wave reductions + LDS accumulate ---
  int lane = tx & 63, wid = tx >> 6;
  auto wsum = [](float v) {
    for (int m = 1; m < 64; m <<= 1) v += __shfl_xor(v, m);
    return v;
  };
  float Se = wsum(acc_e), Sw = wsum(acc_w);
  float Sws[4], Swh[4], Shi[6][4], Ms[6][4];
#pragma unroll
  for (int h = 0; h < 4; h++) { Sws[h] = wsum(acc_ws[h]); Swh[h] = wsum(acc_wh[h]); }
#pragma unroll
  for (int k = 0; k < 6; k++)
#pragma unroll
    for (int h = 0; h < 4; h++) Shi[k][h] = wsum(acc_hi[k][h]);
#pragma unroll
  for (int d = 0; d < 6; d++)
#pragma unroll
    for (int h = 0; h < 4; h++) {
      float v = ((lane >> d) & 1) ? acc_ws[h] : 0.0f;
      Ms[d][h] = wsum(v);
    }
  if (lane == 0) {
    atomicAdd(&sS[0], Se); atomicAdd(&sS[1], Sw);
#pragma unroll
    for (int h = 0; h < 4; h++) { atomicAdd(&sS[2 + h], Sws[h]); atomicAdd(&sS[6 + h], Swh[h]); }
#pragma unroll
    for (int h = 0; h < 4; h++) {
#pragma unroll
      for (int d = 0; d < 6; d++)
        if (Ms[d][h] != 0.0f) atomicAdd(&sS[10 + h * 21 + d], Ms[d][h]);
#pragma unroll
      for (int wb = 0; wb < 4; wb++)
        if ((wid >> wb) & 1) atomicAdd(&sS[10 + h * 21 + 6 + wb], Sws[h]);
      for (int sb = 0; sb < Tlg - 10; sb++)
        if ((sub >> sb) & 1) atomicAdd(&sS[10 + h * 21 + 10 + sb], Sws[h]);
#pragma unroll
      for (int k = 0; k < 6; k++)
        if (Shi[k][h] != 0.0f) atomicAdd(&sS[10 + h * 21 + Tlg + k], Shi[k][h]);
    }
  }
  __syncthreads();
  for (int i = tx; i < SUMS_STRIDE; i += 1024) {
    float v = sS[i];
    if (v != 0.0f) atomicAdd(&ws[OFF_SUMS + t * SUMS_STRIDE + i], v);
  }
}

// =================== Kernel D: finalize gradient outputs ===================
__global__ void kd(const float* W1_2, const float* b1_2, const float* W2_2, const float* b2_2,
                   const float* W1_3, const float* b1_3, const float* W2_3, const float* b2_3,
                   const float* ws, float* out) {
  __shared__ float sk_s[NSTEPS][4], hk_s[NSTEPS][4], pp_s[NSTEPS], s0i_s[NSTEPS];
  int tx = threadIdx.x;
  if (tx < NSTEPS) {
    int t = tx; int g = (t < NSTEP2) ? 0 : 1; int L = g ? L3 : L2;
    const float* W1 = g ? W1_3 : W1_2;
    const float* W2 = g ? W2_3 : W2_2;
    float p = ws[OFF_PCHAIN + t];
    pp_s[t] = p;
    s0i_s[t] = 1.0f / ws[OFF_SUMS + t * SUMS_STRIDE + 0];
    for (int h = 0; h < 4; h++) {
      float hk = fast_tanh(ws[OFF_KEYB + t * 4 + h] + p * W1[h * (L + 1)]);
      hk_s[t][h] = hk;
      sk_s[t][h] = (1.0f - hk * hk) * W2[h];
    }
  }
  __syncthreads();
  const unsigned* cbp = (const unsigned*)ws;
  for (int o = 33 + tx; o < 223; o += blockDim.x) {
    float val = 0.0f;
    if (o < 130) {                           // ---- group2 grads ----
      if (o < 121) {                         // W1_2 grad [4][22]
        int e = o - 33; int h = e / 22, d = e % 22;
        for (int t = 0; t < NSTEP2; t++) {
          float xk = (d == 0) ? pp_s[t] : (float)((cbp[OFF_CB + t] >> (d - 1)) & 1);
          float gs = (d == 0) ? pp_s[t] * ws[OFF_SUMS + t * SUMS_STRIDE + 2 + h]
                              : ws[OFF_SUMS + t * SUMS_STRIDE + 10 + h * 21 + (d - 1)];
          val += sk_s[t][h] * xk - gs * s0i_s[t];
        }
      } else if (o < 125) { int h = o - 121;
        for (int t = 0; t < NSTEP2; t++) val += sk_s[t][h] - ws[OFF_SUMS + t * SUMS_STRIDE + 2 + h] * s0i_s[t];
      } else if (o < 129) { int h = o - 125;
        for (int t = 0; t < NSTEP2; t++) val += hk_s[t][h] - ws[OFF_SUMS + t * SUMS_STRIDE + 6 + h] * s0i_s[t];
      } else {
        for (int t = 0; t < NSTEP2; t++) val += 1.0f - ws[OFF_SUMS + t * SUMS_STRIDE + 1] * s0i_s[t];
      }
    } else {                                 // ---- group3 grads ----
      if (o < 214) {                         // W1_3 grad [4][21]
        int e = o - 130; int h = e / 21, d = e % 21;
        for (int t = NSTEP2; t < NSTEPS; t++) {
          float xk = (d == 0) ? pp_s[t] : (float)((cbp[OFF_CB + t] >> (d - 1)) & 1);
          float gs = (d == 0) ? pp_s[t] * ws[OFF_SUMS + t * SUMS_STRIDE + 2 + h]
                              : ws[OFF_SUMS + t * SUMS_STRIDE + 10 + h * 21 + (d - 1)];
          val += sk_s[t][h] * xk - gs * s0i_s[t];
        }
      } else if (o < 218) { int h = o - 214;
        for (int t = NSTEP2; t < NSTEPS; t++) val += sk_s[t][h] - ws[OFF_SUMS + t * SUMS_STRIDE + 2 + h] * s0i_s[t];
      } else if (o < 222) { int h = o - 218;
        for (int t = NSTEP2; t < NSTEPS; t++) val += hk_s[t][h] - ws[OFF_SUMS + t * SUMS_STRIDE + 6 + h] * s0i_s[t];
      } else {
        for (int t = NSTEP2; t < NSTEPS; t++) val += 1.0f - ws[OFF_SUMS + t * SUMS_STRIDE + 1] * s0i_s[t];
      }
    }
    out[o] = val;
  }
}

extern "C" void kernel_launch(void* const* d_in, const int* in_sizes, int n_in,
                              void* d_out, int out_size, void* d_ws, size_t ws_size,
                              hipStream_t stream) {
  const float* p0   = (const float*)d_in[0];
  const float* sel  = (const float*)d_in[1];
  const float* W1_2 = (const float*)d_in[2]; const float* b1_2 = (const float*)d_in[3];
  const float* W2_2 = (const float*)d_in[4]; const float* b2_2 = (const float*)d_in[5];
  const float* W1_3 = (const float*)d_in[6]; const float* b1_3 = (const float*)d_in[7];
  const float* W2_3 = (const float*)d_in[8]; const float* b2_3 = (const float*)d_in[9];
  float* out = (float*)d_out;
  float* ws  = (float*)d_ws;
  hipLaunchKernelGGL(kz, dim3(1), dim3(256), 0, stream, p0, sel, W1_2, b1_2, W1_3, b1_3, ws);
  hipLaunchKernelGGL(ka, dim3(A_BLOCKS2 + A_BLOCKS3), dim3(1024), 0, stream,
                     W1_2, b1_2, W2_2, b2_2, W1_3, b1_3, W2_3, b2_3, ws);
  hipLaunchKernelGGL(kb, dim3(1), dim3(64), 0, stream, p0,
                     W1_2, b1_2, W2_2, b2_2, W1_3, b1_3, W2_3, b2_3, ws, out);
  hipLaunchKernelGGL(kc, dim3(C_BLOCKS), dim3(1024), 0, stream,
                     W1_2, b1_2, W2_2, b2_2, W1_3, b1_3, W2_3, b2_3, ws);
  hipLaunchKernelGGL(kd, dim3(1), dim3(256), 0, stream,
                     W1_2, b1_2, W2_2, b2_2, W1_3, b1_3, W2_3, b2_3, ws, out);
}

// Round 3
// 259.518 us; speedup vs baseline: 1.3595x; 1.3595x over previous
//
#include <hip/hip_runtime.h>
#include <cstdint>
#include <cmath>

#define DEV __device__ __forceinline__

constexpr int SEL = 20;
constexpr int NSTEP2 = 10, NSTEP3 = 22, NSTEPS = 32;
constexpr int L2 = SEL + 1;   // 21 bits, group2
constexpr int L3 = SEL;       // 20 bits, group3
constexpr int H = 4;
constexpr int P = 8;          // Chebyshev probes

// ---- ws layout (float indices) ----
constexpr int OFF_T      = 0;                               // T[2][22][P] = 352
constexpr int OFF_SUMS   = OFF_T + 2 * 22 * P;              // 352
constexpr int SUMS_STRIDE = 96;                             // [0]=Se [1]=Sw [2..5]=Sws [6..9]=Swh [10+h*21+d]=GW1
constexpr int OFF_PCHAIN = OFF_SUMS + NSTEPS * SUMS_STRIDE; // pchain[33]
constexpr int OFF_KEYB   = OFF_PCHAIN + 40;                 // keybase[32][4]
constexpr int OFF_CT     = OFF_KEYB + 128;                  // int c_t[32]
constexpr int OFF_CB     = OFF_CT + 32;                     // uint chunkbits[32]
constexpr int OFF_NEED   = OFF_CB + 32;                     // uint neededmask[2]
constexpr int WS_FLOATS  = OFF_NEED + 8;

__constant__ float CHEB_P[P] = {0.9903926402f, 0.9157348062f, 0.7777851165f, 0.5975451610f,
                                0.4024548390f, 0.2222148835f, 0.0842651938f, 0.0096073598f};
__constant__ float CHEB_W[P] = {0.1950903220f, -0.5555702330f, 0.8314696123f, -0.9807852804f,
                                0.9807852804f, -0.8314696123f, 0.5555702330f, -0.1950903220f};

struct Binom { unsigned v[22][22]; };
constexpr Binom make_binom() {
  Binom b{};
  for (int n = 0; n < 22; n++) {
    b.v[n][0] = 1;
    for (int k = 1; k < 22; k++)
      b.v[n][k] = (k > n) ? 0u : (k == n ? 1u : b.v[n - 1][k - 1] + b.v[n - 1][k]);
  }
  return b;
}
constexpr Binom BN_H = make_binom();              // host/compile-time
__device__ constexpr Binom BN = make_binom();     // device runtime table

DEV float fast_tanh(float x) {
  float e = exp2f(x * 2.8853900817779268f);  // e^(2x)
  return 1.0f - 2.0f * __builtin_amdgcn_rcpf(e + 1.0f);
}
DEV float fast_exp(float x) { return exp2f(x * 1.4426950408889634f); }

DEV unsigned gosper(unsigned cmb) {
  unsigned u = cmb & (~cmb + 1u);
  unsigned v = cmb + u;
  return v | ((cmb ^ v) >> (1 + __ffs(u)));
}

// colex unrank: rank r within class (L choose c) -> bit pattern
DEV unsigned unrank_lds(const unsigned* sBN, int L, int c, unsigned r) {
  unsigned cmb = 0; int kk = c;
  for (int bb = L - 1; bb >= 0 && kk > 0; bb--) {
    unsigned cnt = sBN[bb * 22 + kk];
    if (r >= cnt) { cmb |= 1u << bb; r -= cnt; kk--; }
  }
  return cmb;
}

constexpr unsigned cdiv_u(unsigned a, unsigned b) { return (a + b - 1) / b; }

// =================== Kernel Z: init / decode chunks ===================
__global__ void kz(const float* p0, const float* sel,
                   const float* W1_2, const float* b1_2,
                   const float* W1_3, const float* b1_3, float* ws) {
  int t = threadIdx.x;
  for (int i = t; i < WS_FLOATS; i += blockDim.x) ws[i] = 0.0f;
  __syncthreads();
  if (t < NSTEPS) {
    int g = (t < NSTEP2) ? 0 : 1;
    int L = g ? L3 : L2;
    const float* sbase = sel + (g ? (NSTEP2 * L2 + (t - NSTEP2) * L3) : t * L2);
    unsigned cb = 0; int c = 0;
    for (int d = 0; d < L; d++)
      if (sbase[d] > 0.5f) { cb |= 1u << d; c++; }
    ((int*)ws)[OFF_CT + t] = c;
    ((unsigned*)ws)[OFF_CB + t] = cb;
    atomicOr(&((unsigned*)ws)[OFF_NEED + g], 1u << c);
    const float* W1 = g ? W1_3 : W1_2;
    const float* b1 = g ? b1_3 : b1_2;
    for (int h = 0; h < H; h++) {
      float s = b1[h];
      for (int d = 0; d < L; d++)
        if ((cb >> d) & 1) s += W1[h * (L + 1) + 1 + d];
      ws[OFF_KEYB + t * 4 + h] = s;
    }
    if (t == 0) ws[OFF_PCHAIN] = p0[0];
  }
}

// =================== Kernel A: per-class tabulation of T[g][c][j] ===================
constexpr int KA_CPT = 32;
constexpr int KA_RPB = 256 * KA_CPT; // 8192 ranks per block

struct KaOff { int off2[23]; int off3[22]; int total2; int total; };
constexpr KaOff make_kaoff() {
  KaOff o{};
  int cum = 0;
  for (int c = 0; c <= 21; c++) { o.off2[c] = cum; cum += (int)cdiv_u(BN_H.v[21][c], KA_RPB); }
  o.off2[22] = cum; o.total2 = cum;
  int cum3 = 0;
  for (int c = 0; c <= 20; c++) { o.off3[c] = cum3; cum3 += (int)cdiv_u(BN_H.v[20][c], KA_RPB); }
  o.off3[21] = cum3;
  o.total = cum + cum3;
  return o;
}
constexpr KaOff KAOFF = make_kaoff();

template<int LL>
DEV void ka_work(int g, int c, int sub,
                 const float* W1, const float* b1, const float* W2, const float* b2,
                 float* ws, unsigned* sBN, float4* tab0, float4* tab1, float4* tab2) {
  int tx = threadIdx.x;
  const unsigned* bnf = &BN.v[0][0];
  for (int i = tx; i < 484; i += 256) sBN[i] = bnf[i];
  for (int i = tx; i < 384; i += 256) {
    int which = i >> 7, e = i & 127;
    int lo = which * 7; int nb = (which < 2) ? 7 : (LL - 14);
    float4 v; float* vp = (float*)&v;
    for (int h = 0; h < 4; h++) {
      float s = (which == 0) ? b1[h] : 0.0f;
      for (int j = 0; j < nb; j++)
        if ((e >> j) & 1) s += W1[h * (LL + 1) + 1 + lo + j];
      vp[h] = s;
    }
    if (which == 0) tab0[e] = v; else if (which == 1) tab1[e] = v; else tab2[e] = v;
  }
  __syncthreads();
  float a0 = W1[0], a1 = W1[LL + 1], a2 = W1[2 * (LL + 1)], a3 = W1[3 * (LL + 1)];
  float w0 = W2[0], w1 = W2[1], w2 = W2[2], w3 = W2[3];
  float b2s = b2[0];
  float pa[P][4];
#pragma unroll
  for (int j = 0; j < P; j++) {
    pa[j][0] = CHEB_P[j] * a0; pa[j][1] = CHEB_P[j] * a1;
    pa[j][2] = CHEB_P[j] * a2; pa[j][3] = CHEB_P[j] * a3;
  }
  unsigned C = BN.v[LL][c];
  unsigned r0 = (unsigned)sub * KA_RPB + (unsigned)tx * KA_CPT;
  int nI = (int)C - (int)r0;
  if (nI > KA_CPT) nI = KA_CPT;
  unsigned cmb = (nI > 0) ? unrank_lds(sBN, LL, c, r0) : 0u;
  float acc[P];
#pragma unroll
  for (int j = 0; j < P; j++) acc[j] = 0.0f;
#pragma unroll 1
  for (int k = 0; k < nI; k++) {
    unsigned n = cmb;
    float4 v0 = tab0[n & 127], v1 = tab1[(n >> 7) & 127], v2 = tab2[(n >> 14) & 127];
    float base0 = v0.x + v1.x + v2.x, base1 = v0.y + v1.y + v2.y;
    float base2 = v0.z + v1.z + v2.z, base3 = v0.w + v1.w + v2.w;
#pragma unroll
    for (int j = 0; j < P; j++) {
      float t0 = fast_tanh(base0 + pa[j][0]);
      float t1 = fast_tanh(base1 + pa[j][1]);
      float t2 = fast_tanh(base2 + pa[j][2]);
      float t3 = fast_tanh(base3 + pa[j][3]);
      float outv = b2s + w0 * t0 + w1 * t1 + w2 * t2 + w3 * t3;
      acc[j] += fast_exp(outv);
    }
    cmb = gosper(cmb);
  }
#pragma unroll
  for (int j = 0; j < P; j++) {
    float v = acc[j];
    for (int m = 1; m < 64; m <<= 1) v += __shfl_xor(v, m);
    if ((tx & 63) == 0 && v != 0.0f) atomicAdd(&ws[OFF_T + g * 22 * P + c * P + j], v);
  }
}

__global__ __launch_bounds__(256) void ka(
    const float* W1_2, const float* b1_2, const float* W2_2, const float* b2_2,
    const float* W1_3, const float* b1_3, const float* W2_3, const float* b2_3,
    float* ws) {
  __shared__ unsigned sBN[484];
  __shared__ float4 tab0[128], tab1[128], tab2[128];
  int b = blockIdx.x;
  int g, c = 0, sub;
  if (b < KAOFF.total2) {
    g = 0;
#pragma unroll
    for (int cc = 1; cc <= 21; cc++) if (b >= KAOFF.off2[cc]) c = cc;
    sub = b - KAOFF.off2[c];
  } else {
    g = 1; int b3 = b - KAOFF.total2;
#pragma unroll
    for (int cc = 1; cc <= 20; cc++) if (b3 >= KAOFF.off3[cc]) c = cc;
    sub = b3 - KAOFF.off3[c];
  }
  unsigned need = ((const unsigned*)ws)[OFF_NEED + g];
  if (!((need >> c) & 1)) return;
  if (g == 0) ka_work<21>(0, c, sub, W1_2, b1_2, W2_2, b2_2, ws, sBN, tab0, tab1, tab2);
  else        ka_work<20>(1, c, sub, W1_3, b1_3, W2_3, b2_3, ws, sBN, tab0, tab1, tab2);
}

// =================== Kernel B: sequential prob chain via Chebyshev interp ===================
__global__ void kb(const float* p0in,
                   const float* W1_2, const float* b1_2, const float* W2_2, const float* b2_2,
                   const float* W1_3, const float* b1_3, const float* W2_3, const float* b2_3,
                   float* ws, float* out) {
  if (threadIdx.x != 0) return;
  float p = p0in[0];
  out[0] = p;
  ws[OFF_PCHAIN] = p;
  for (int tt = 0; tt < NSTEPS; tt++) {
    int g = (tt < NSTEP2) ? 0 : 1;
    int L = g ? L3 : L2;
    const float* W1 = g ? W1_3 : W1_2;
    const float* W2 = g ? W2_3 : W2_2;
    float b2s = (g ? b2_3 : b2_2)[0];
    int c = ((const int*)ws)[OFF_CT + tt];
    float outk = b2s;
    for (int h = 0; h < H; h++) {
      float hk = fast_tanh(ws[OFF_KEYB + tt * 4 + h] + p * W1[h * (L + 1)]);
      outk += W2[h] * hk;
    }
    const float* T = &ws[OFF_T + g * 22 * P + c * P];
    float num = 0.0f, den = 0.0f, Sehit = 0.0f;
    bool hit = false;
#pragma unroll
    for (int j = 0; j < P; j++) {
      float d = p - CHEB_P[j];
      if (fabsf(d) < 1e-8f) { hit = true; Sehit = T[j]; }
      else { float q = CHEB_W[j] / d; num += q * T[j]; den += q; }
    }
    float Se = hit ? Sehit : (num / den);
    p = fast_exp(outk) / Se;
    ws[OFF_PCHAIN + 1 + tt] = p;
    out[1 + tt] = p;
  }
}

// =================== Kernel C: exact per-class 94-sum reductions ===================
constexpr int KC_CPT = 32;
constexpr int KC_RPB = 256 * KC_CPT; // 8192
constexpr int KC_B2 = (int)cdiv_u(BN_H.v[21][10], KC_RPB); // 44 (max C(21,c)=352716)
constexpr int KC_B3 = (int)cdiv_u(BN_H.v[20][10], KC_RPB); // 23 (max C(20,c)=184756)
constexpr int KC_BLOCKS = NSTEP2 * KC_B2 + NSTEP3 * KC_B3; // 946

template<int LL>
DEV void kc_work(int t, int sub,
                 const float* W1, const float* b1, const float* W2, const float* b2,
                 float* ws, unsigned* sBN, float4* tab0, float4* tab1, float4* tab2) {
  int tx = threadIdx.x;
  int c = ((const int*)ws)[OFF_CT + t];
  unsigned C = BN.v[LL][c];
  unsigned rank0 = (unsigned)sub * KC_RPB;
  if (rank0 >= C) return;   // block-uniform early exit (before any barrier)
  const unsigned* bnf = &BN.v[0][0];
  for (int i = tx; i < 484; i += 256) sBN[i] = bnf[i];
  for (int i = tx; i < 384; i += 256) {
    int which = i >> 7, e = i & 127;
    int lo = which * 7; int nb = (which < 2) ? 7 : (LL - 14);
    float4 v; float* vp = (float*)&v;
    for (int h = 0; h < 4; h++) {
      float s = (which == 0) ? b1[h] : 0.0f;
      for (int j = 0; j < nb; j++)
        if ((e >> j) & 1) s += W1[h * (LL + 1) + 1 + lo + j];
      vp[h] = s;
    }
    if (which == 0) tab0[e] = v; else if (which == 1) tab1[e] = v; else tab2[e] = v;
  }
  __syncthreads();
  float p = ws[OFF_PCHAIN + t];
  float a0 = W1[0], a1 = W1[LL + 1], a2 = W1[2 * (LL + 1)], a3 = W1[3 * (LL + 1)];
  float pa0 = p * a0, pa1 = p * a1, pa2 = p * a2, pa3 = p * a3;
  float w0 = W2[0], w1 = W2[1], w2 = W2[2], w3 = W2[3];
  float b2s = b2[0];
  unsigned r0 = rank0 + (unsigned)tx * KC_CPT;
  int nI = (int)C - (int)r0;
  if (nI > KC_CPT) nI = KC_CPT;
  unsigned cmb = (nI > 0) ? unrank_lds(sBN, LL, c, r0) : 0u;

  float aE = 0.0f, aW = 0.0f;
  float aQ[4] = {0, 0, 0, 0}, aWH[4] = {0, 0, 0, 0};
  float aG[LL][4];
#pragma unroll
  for (int d = 0; d < LL; d++)
#pragma unroll
    for (int h = 0; h < 4; h++) aG[d][h] = 0.0f;

#pragma unroll 1
  for (int k = 0; k < nI; k++) {
    unsigned n = cmb;
    float4 v0 = tab0[n & 127], v1 = tab1[(n >> 7) & 127], v2 = tab2[(n >> 14) & 127];
    float t0 = fast_tanh(v0.x + v1.x + v2.x + pa0);
    float t1 = fast_tanh(v0.y + v1.y + v2.y + pa1);
    float t2 = fast_tanh(v0.z + v1.z + v2.z + pa2);
    float t3 = fast_tanh(v0.w + v1.w + v2.w + pa3);
    float outv = b2s + w0 * t0 + w1 * t1 + w2 * t2 + w3 * t3;
    float e = fast_exp(outv);
    float s0 = (1.0f - t0 * t0) * w0, s1 = (1.0f - t1 * t1) * w1;
    float s2 = (1.0f - t2 * t2) * w2, s3 = (1.0f - t3 * t3) * w3;
    float q0 = outv * s0, q1 = outv * s1, q2 = outv * s2, q3 = outv * s3;
    aE += e; aW += outv;
    aQ[0] += q0; aQ[1] += q1; aQ[2] += q2; aQ[3] += q3;
    aWH[0] += outv * t0; aWH[1] += outv * t1; aWH[2] += outv * t2; aWH[3] += outv * t3;
#pragma unroll
    for (int d = 0; d < LL; d++) {
      float bd = (float)((n >> d) & 1u);
      aG[d][0] = fmaf(bd, q0, aG[d][0]);
      aG[d][1] = fmaf(bd, q1, aG[d][1]);
      aG[d][2] = fmaf(bd, q2, aG[d][2]);
      aG[d][3] = fmaf(bd, q3, aG[d][3]);
    }
    cmb = gosper(cmb);
  }

  // wave reductions + global atomics
  auto wsum = [](float v) {
    for (int m = 1; m < 64; m <<= 1) v += __shfl_xor(v, m);
    return v;
  };
  int lane = tx & 63;
  float* S = &ws[OFF_SUMS + t * SUMS_STRIDE];
  float r;
  r = wsum(aE); if (lane == 0 && r != 0.0f) atomicAdd(&S[0], r);
  r = wsum(aW); if (lane == 0 && r != 0.0f) atomicAdd(&S[1], r);
#pragma unroll
  for (int h = 0; h < 4; h++) {
    r = wsum(aQ[h]);  if (lane == 0 && r != 0.0f) atomicAdd(&S[2 + h], r);
    r = wsum(aWH[h]); if (lane == 0 && r != 0.0f) atomicAdd(&S[6 + h], r);
  }
#pragma unroll
  for (int d = 0; d < LL; d++)
#pragma unroll
    for (int h = 0; h < 4; h++) {
      r = wsum(aG[d][h]);
      if (lane == 0 && r != 0.0f) atomicAdd(&S[10 + h * 21 + d], r);
    }
}

__global__ __launch_bounds__(256) void kc(
    const float* W1_2, const float* b1_2, const float* W2_2, const float* b2_2,
    const float* W1_3, const float* b1_3, const float* W2_3, const float* b2_3,
    float* ws) {
  __shared__ unsigned sBN[484];
  __shared__ float4 tab0[128], tab1[128], tab2[128];
  int b = blockIdx.x;
  if (b < NSTEP2 * KC_B2) {
    int t = b / KC_B2, sub = b % KC_B2;
    kc_work<21>(t, sub, W1_2, b1_2, W2_2, b2_2, ws, sBN, tab0, tab1, tab2);
  } else {
    int bb = b - NSTEP2 * KC_B2;
    int t = NSTEP2 + bb / KC_B3, sub = bb % KC_B3;
    kc_work<20>(t, sub, W1_3, b1_3, W2_3, b2_3, ws, sBN, tab0, tab1, tab2);
  }
}

// =================== Kernel D: finalize gradient outputs ===================
__global__ void kd(const float* W1_2, const float* b1_2, const float* W2_2, const float* b2_2,
                   const float* W1_3, const float* b1_3, const float* W2_3, const float* b2_3,
                   const float* ws, float* out) {
  __shared__ float sk_s[NSTEPS][4], hk_s[NSTEPS][4], pp_s[NSTEPS], s0i_s[NSTEPS];
  int tx = threadIdx.x;
  if (tx < NSTEPS) {
    int t = tx; int g = (t < NSTEP2) ? 0 : 1; int L = g ? L3 : L2;
    const float* W1 = g ? W1_3 : W1_2;
    const float* W2 = g ? W2_3 : W2_2;
    float p = ws[OFF_PCHAIN + t];
    pp_s[t] = p;
    s0i_s[t] = 1.0f / ws[OFF_SUMS + t * SUMS_STRIDE + 0];
    for (int h = 0; h < 4; h++) {
      float hk = fast_tanh(ws[OFF_KEYB + t * 4 + h] + p * W1[h * (L + 1)]);
      hk_s[t][h] = hk;
      sk_s[t][h] = (1.0f - hk * hk) * W2[h];
    }
  }
  __syncthreads();
  const unsigned* cbp = (const unsigned*)ws;
  for (int o = 33 + tx; o < 223; o += blockDim.x) {
    float val = 0.0f;
    if (o < 130) {                           // ---- group2 grads ----
      if (o < 121) {                         // W1_2 grad [4][22]
        int e = o - 33; int h = e / 22, d = e % 22;
        for (int t = 0; t < NSTEP2; t++) {
          float xk = (d == 0) ? pp_s[t] : (float)((cbp[OFF_CB + t] >> (d - 1)) & 1);
          float gs = (d == 0) ? pp_s[t] * ws[OFF_SUMS + t * SUMS_STRIDE + 2 + h]
                              : ws[OFF_SUMS + t * SUMS_STRIDE + 10 + h * 21 + (d - 1)];
          val += sk_s[t][h] * xk - gs * s0i_s[t];
        }
      } else if (o < 125) { int h = o - 121;
        for (int t = 0; t < NSTEP2; t++) val += sk_s[t][h] - ws[OFF_SUMS + t * SUMS_STRIDE + 2 + h] * s0i_s[t];
      } else if (o < 129) { int h = o - 125;
        for (int t = 0; t < NSTEP2; t++) val += hk_s[t][h] - ws[OFF_SUMS + t * SUMS_STRIDE + 6 + h] * s0i_s[t];
      } else {
        for (int t = 0; t < NSTEP2; t++) val += 1.0f - ws[OFF_SUMS + t * SUMS_STRIDE + 1] * s0i_s[t];
      }
    } else {                                 // ---- group3 grads ----
      if (o < 214) {                         // W1_3 grad [4][21]
        int e = o - 130; int h = e / 21, d = e % 21;
        for (int t = NSTEP2; t < NSTEPS; t++) {
          float xk = (d == 0) ? pp_s[t] : (float)((cbp[OFF_CB + t] >> (d - 1)) & 1);
          float gs = (d == 0) ? pp_s[t] * ws[OFF_SUMS + t * SUMS_STRIDE + 2 + h]
                              : ws[OFF_SUMS + t * SUMS_STRIDE + 10 + h * 21 + (d - 1)];
          val += sk_s[t][h] * xk - gs * s0i_s[t];
        }
      } else if (o < 218) { int h = o - 214;
        for (int t = NSTEP2; t < NSTEPS; t++) val += sk_s[t][h] - ws[OFF_SUMS + t * SUMS_STRIDE + 2 + h] * s0i_s[t];
      } else if (o < 222) { int h = o - 218;
        for (int t = NSTEP2; t < NSTEPS; t++) val += hk_s[t][h] - ws[OFF_SUMS + t * SUMS_STRIDE + 6 + h] * s0i_s[t];
      } else {
        for (int t = NSTEP2; t < NSTEPS; t++) val += 1.0f - ws[OFF_SUMS + t * SUMS_STRIDE + 1] * s0i_s[t];
      }
    }
    out[o] = val;
  }
}

extern "C" void kernel_launch(void* const* d_in, const int* in_sizes, int n_in,
                              void* d_out, int out_size, void* d_ws, size_t ws_size,
                              hipStream_t stream) {
  const float* p0   = (const float*)d_in[0];
  const float* sel  = (const float*)d_in[1];
  const float* W1_2 = (const float*)d_in[2]; const float* b1_2 = (const float*)d_in[3];
  const float* W2_2 = (const float*)d_in[4]; const float* b2_2 = (const float*)d_in[5];
  const float* W1_3 = (const float*)d_in[6]; const float* b1_3 = (const float*)d_in[7];
  const float* W2_3 = (const float*)d_in[8]; const float* b2_3 = (const float*)d_in[9];
  float* out = (float*)d_out;
  float* ws  = (float*)d_ws;
  hipLaunchKernelGGL(kz, dim3(1), dim3(256), 0, stream, p0, sel, W1_2, b1_2, W1_3, b1_3, ws);
  hipLaunchKernelGGL(ka, dim3(KAOFF.total), dim3(256), 0, stream,
                     W1_2, b1_2, W2_2, b2_2, W1_3, b1_3, W2_3, b2_3, ws);
  hipLaunchKernelGGL(kb, dim3(1), dim3(64), 0, stream, p0,
                     W1_2, b1_2, W2_2, b2_2, W1_3, b1_3, W2_3, b2_3, ws, out);
  hipLaunchKernelGGL(kc, dim3(KC_BLOCKS), dim3(256), 0, stream,
                     W1_2, b1_2, W2_2, b2_2, W1_3, b1_3, W2_3, b2_3, ws);
  hipLaunchKernelGGL(kd, dim3(1), dim3(256), 0, stream,
                     W1_2, b1_2, W2_2, b2_2, W1_3, b1_3, W2_3, b2_3, ws, out);
}

// Round 4
// 259.038 us; speedup vs baseline: 1.3621x; 1.0019x over previous
//
#include <hip/hip_runtime.h>
#include <cstdint>
#include <cmath>

#define DEV __device__ __forceinline__

constexpr int SEL = 20;
constexpr int NSTEP2 = 10, NSTEP3 = 22, NSTEPS = 32;
constexpr int L2 = SEL + 1;   // 21 bits, group2
constexpr int L3 = SEL;       // 20 bits, group3
constexpr int H = 4;
constexpr int P = 8;          // Chebyshev probes

// ---- ws layout (float indices) ----
constexpr int OFF_T      = 0;                               // T[2][22][P] = 352
constexpr int OFF_SUMS   = OFF_T + 2 * 22 * P;              // 352
constexpr int SUMS_STRIDE = 96;                             // [0]=Se [1]=Sw [2..5]=Sws [6..9]=Swh [10+h*21+d]=GW1
constexpr int OFF_PCHAIN = OFF_SUMS + NSTEPS * SUMS_STRIDE; // pchain[33]
constexpr int OFF_KEYB   = OFF_PCHAIN + 40;                 // keybase[32][4]
constexpr int OFF_CT     = OFF_KEYB + 128;                  // int c_t[32]
constexpr int OFF_CB     = OFF_CT + 32;                     // uint chunkbits[32]
constexpr int OFF_NEED   = OFF_CB + 32;                     // uint neededmask[2]
constexpr int WS_FLOATS  = OFF_NEED + 8;

__constant__ float CHEB_P[P] = {0.9903926402f, 0.9157348062f, 0.7777851165f, 0.5975451610f,
                                0.4024548390f, 0.2222148835f, 0.0842651938f, 0.0096073598f};
__constant__ float CHEB_W[P] = {0.1950903220f, -0.5555702330f, 0.8314696123f, -0.9807852804f,
                                0.9807852804f, -0.8314696123f, 0.5555702330f, -0.1950903220f};

struct Binom { unsigned v[22][22]; };
constexpr Binom make_binom() {
  Binom b{};
  for (int n = 0; n < 22; n++) {
    b.v[n][0] = 1;
    for (int k = 1; k < 22; k++)
      b.v[n][k] = (k > n) ? 0u : (k == n ? 1u : b.v[n - 1][k - 1] + b.v[n - 1][k]);
  }
  return b;
}
constexpr Binom BN_H = make_binom();              // host/compile-time
__device__ constexpr Binom BN = make_binom();     // device runtime table

DEV float fast_tanh(float x) {
  float e = exp2f(x * 2.8853900817779268f);  // e^(2x)
  return 1.0f - 2.0f * __builtin_amdgcn_rcpf(e + 1.0f);
}
DEV float fast_exp(float x) { return exp2f(x * 1.4426950408889634f); }

DEV unsigned gosper(unsigned cmb) {
  unsigned u = cmb & (~cmb + 1u);
  unsigned v = cmb + u;
  return v | ((cmb ^ v) >> (1 + __ffs(u)));
}

// colex unrank: rank r within class (L choose c) -> bit pattern
DEV unsigned unrank_lds(const unsigned* sBN, int L, int c, unsigned r) {
  unsigned cmb = 0; int kk = c;
  for (int bb = L - 1; bb >= 0 && kk > 0; bb--) {
    unsigned cnt = sBN[bb * 22 + kk];
    if (r >= cnt) { cmb |= 1u << bb; r -= cnt; kk--; }
  }
  return cmb;
}

constexpr unsigned cdiv_u(unsigned a, unsigned b) { return (a + b - 1) / b; }

// =================== Kernel Z: init / decode chunks ===================
__global__ void kz(const float* p0, const float* sel,
                   const float* W1_2, const float* b1_2,
                   const float* W1_3, const float* b1_3, float* ws) {
  int t = threadIdx.x;
  for (int i = t; i < WS_FLOATS; i += blockDim.x) ws[i] = 0.0f;
  __syncthreads();
  if (t < NSTEPS) {
    int g = (t < NSTEP2) ? 0 : 1;
    int L = g ? L3 : L2;
    const float* sbase = sel + (g ? (NSTEP2 * L2 + (t - NSTEP2) * L3) : t * L2);
    unsigned cb = 0; int c = 0;
    for (int d = 0; d < L; d++)
      if (sbase[d] > 0.5f) { cb |= 1u << d; c++; }
    ((int*)ws)[OFF_CT + t] = c;
    ((unsigned*)ws)[OFF_CB + t] = cb;
    atomicOr(&((unsigned*)ws)[OFF_NEED + g], 1u << c);
    const float* W1 = g ? W1_3 : W1_2;
    const float* b1 = g ? b1_3 : b1_2;
    for (int h = 0; h < H; h++) {
      float s = b1[h];
      for (int d = 0; d < L; d++)
        if ((cb >> d) & 1) s += W1[h * (L + 1) + 1 + d];
      ws[OFF_KEYB + t * 4 + h] = s;
    }
    if (t == 0) ws[OFF_PCHAIN] = p0[0];
  }
}

// =================== Kernel A: per-class tabulation of T[g][c][j] ===================
constexpr int KA_CPT = 32;
constexpr int KA_RPB = 256 * KA_CPT; // 8192 ranks per block

struct KaOff { int off2[23]; int off3[22]; int total2; int total; };
constexpr KaOff make_kaoff() {
  KaOff o{};
  int cum = 0;
  for (int c = 0; c <= 21; c++) { o.off2[c] = cum; cum += (int)cdiv_u(BN_H.v[21][c], KA_RPB); }
  o.off2[22] = cum; o.total2 = cum;
  int cum3 = 0;
  for (int c = 0; c <= 20; c++) { o.off3[c] = cum3; cum3 += (int)cdiv_u(BN_H.v[20][c], KA_RPB); }
  o.off3[21] = cum3;
  o.total = cum + cum3;
  return o;
}
constexpr KaOff KAOFF = make_kaoff();

template<int LL>
DEV void ka_work(int g, int c, int sub,
                 const float* W1, const float* b1, const float* W2, const float* b2,
                 float* ws, unsigned* sBN, float4* tab0, float4* tab1, float4* tab2) {
  int tx = threadIdx.x;
  const unsigned* bnf = &BN.v[0][0];
  for (int i = tx; i < 484; i += 256) sBN[i] = bnf[i];
  for (int i = tx; i < 384; i += 256) {
    int which = i >> 7, e = i & 127;
    int lo = which * 7; int nb = (which < 2) ? 7 : (LL - 14);
    float4 v; float* vp = (float*)&v;
    for (int h = 0; h < 4; h++) {
      float s = (which == 0) ? b1[h] : 0.0f;
      for (int j = 0; j < nb; j++)
        if ((e >> j) & 1) s += W1[h * (LL + 1) + 1 + lo + j];
      vp[h] = s;
    }
    if (which == 0) tab0[e] = v; else if (which == 1) tab1[e] = v; else tab2[e] = v;
  }
  __syncthreads();
  float a0 = W1[0], a1 = W1[LL + 1], a2 = W1[2 * (LL + 1)], a3 = W1[3 * (LL + 1)];
  float w0 = W2[0], w1 = W2[1], w2 = W2[2], w3 = W2[3];
  float b2s = b2[0];
  float pa[P][4];
#pragma unroll
  for (int j = 0; j < P; j++) {
    pa[j][0] = CHEB_P[j] * a0; pa[j][1] = CHEB_P[j] * a1;
    pa[j][2] = CHEB_P[j] * a2; pa[j][3] = CHEB_P[j] * a3;
  }
  unsigned C = BN.v[LL][c];
  unsigned r0 = (unsigned)sub * KA_RPB + (unsigned)tx * KA_CPT;
  int nI = (int)C - (int)r0;
  if (nI > KA_CPT) nI = KA_CPT;
  unsigned cmb = (nI > 0) ? unrank_lds(sBN, LL, c, r0) : 0u;
  float acc[P];
#pragma unroll
  for (int j = 0; j < P; j++) acc[j] = 0.0f;
#pragma unroll 1
  for (int k = 0; k < nI; k++) {
    unsigned n = cmb;
    float4 v0 = tab0[n & 127], v1 = tab1[(n >> 7) & 127], v2 = tab2[(n >> 14) & 127];
    float base0 = v0.x + v1.x + v2.x, base1 = v0.y + v1.y + v2.y;
    float base2 = v0.z + v1.z + v2.z, base3 = v0.w + v1.w + v2.w;
#pragma unroll
    for (int j = 0; j < P; j++) {
      float t0 = fast_tanh(base0 + pa[j][0]);
      float t1 = fast_tanh(base1 + pa[j][1]);
      float t2 = fast_tanh(base2 + pa[j][2]);
      float t3 = fast_tanh(base3 + pa[j][3]);
      float outv = b2s + w0 * t0 + w1 * t1 + w2 * t2 + w3 * t3;
      acc[j] += fast_exp(outv);
    }
    cmb = gosper(cmb);
  }
#pragma unroll
  for (int j = 0; j < P; j++) {
    float v = acc[j];
    for (int m = 1; m < 64; m <<= 1) v += __shfl_xor(v, m);
    if ((tx & 63) == 0 && v != 0.0f) atomicAdd(&ws[OFF_T + g * 22 * P + c * P + j], v);
  }
}

__global__ __launch_bounds__(256, 2) void ka(
    const float* W1_2, const float* b1_2, const float* W2_2, const float* b2_2,
    const float* W1_3, const float* b1_3, const float* W2_3, const float* b2_3,
    float* ws) {
  __shared__ unsigned sBN[484];
  __shared__ float4 tab0[128], tab1[128], tab2[128];
  int b = blockIdx.x;
  int g, c = 0, sub;
  if (b < KAOFF.total2) {
    g = 0;
#pragma unroll
    for (int cc = 1; cc <= 21; cc++) if (b >= KAOFF.off2[cc]) c = cc;
    sub = b - KAOFF.off2[c];
  } else {
    g = 1; int b3 = b - KAOFF.total2;
#pragma unroll
    for (int cc = 1; cc <= 20; cc++) if (b3 >= KAOFF.off3[cc]) c = cc;
    sub = b3 - KAOFF.off3[c];
  }
  unsigned need = ((const unsigned*)ws)[OFF_NEED + g];
  if (!((need >> c) & 1)) return;
  if (g == 0) ka_work<21>(0, c, sub, W1_2, b1_2, W2_2, b2_2, ws, sBN, tab0, tab1, tab2);
  else        ka_work<20>(1, c, sub, W1_3, b1_3, W2_3, b2_3, ws, sBN, tab0, tab1, tab2);
}

// =================== Kernel B: sequential prob chain via Chebyshev interp ===================
__global__ void kb(const float* p0in,
                   const float* W1_2, const float* b1_2, const float* W2_2, const float* b2_2,
                   const float* W1_3, const float* b1_3, const float* W2_3, const float* b2_3,
                   float* ws, float* out) {
  if (threadIdx.x != 0) return;
  float p = p0in[0];
  out[0] = p;
  ws[OFF_PCHAIN] = p;
  for (int tt = 0; tt < NSTEPS; tt++) {
    int g = (tt < NSTEP2) ? 0 : 1;
    int L = g ? L3 : L2;
    const float* W1 = g ? W1_3 : W1_2;
    const float* W2 = g ? W2_3 : W2_2;
    float b2s = (g ? b2_3 : b2_2)[0];
    int c = ((const int*)ws)[OFF_CT + tt];
    float outk = b2s;
    for (int h = 0; h < H; h++) {
      float hk = fast_tanh(ws[OFF_KEYB + tt * 4 + h] + p * W1[h * (L + 1)]);
      outk += W2[h] * hk;
    }
    const float* T = &ws[OFF_T + g * 22 * P + c * P];
    float num = 0.0f, den = 0.0f, Sehit = 0.0f;
    bool hit = false;
#pragma unroll
    for (int j = 0; j < P; j++) {
      float d = p - CHEB_P[j];
      if (fabsf(d) < 1e-8f) { hit = true; Sehit = T[j]; }
      else { float q = CHEB_W[j] / d; num += q * T[j]; den += q; }
    }
    float Se = hit ? Sehit : (num / den);
    p = fast_exp(outk) / Se;
    ws[OFF_PCHAIN + 1 + tt] = p;
    out[1 + tt] = p;
  }
}

// =================== Kernel C: exact per-class 94-sum reductions ===================
constexpr int KC_CPT = 32;
constexpr int KC_RPB = 256 * KC_CPT; // 8192
constexpr int KC_B2 = (int)cdiv_u(BN_H.v[21][10], KC_RPB); // 44 (max C(21,c)=352716)
constexpr int KC_B3 = (int)cdiv_u(BN_H.v[20][10], KC_RPB); // 23 (max C(20,c)=184756)
constexpr int KC_BLOCKS = NSTEP2 * KC_B2 + NSTEP3 * KC_B3; // 946

template<int LL>
DEV void kc_work(int t, int sub,
                 const float* W1, const float* b1, const float* W2, const float* b2,
                 float* ws, unsigned* sBN, float4* tab0, float4* tab1, float4* tab2) {
  int tx = threadIdx.x;
  int c = ((const int*)ws)[OFF_CT + t];
  unsigned C = BN.v[LL][c];
  unsigned rank0 = (unsigned)sub * KC_RPB;
  if (rank0 >= C) return;   // block-uniform early exit (before any barrier)
  const unsigned* bnf = &BN.v[0][0];
  for (int i = tx; i < 484; i += 256) sBN[i] = bnf[i];
  for (int i = tx; i < 384; i += 256) {
    int which = i >> 7, e = i & 127;
    int lo = which * 7; int nb = (which < 2) ? 7 : (LL - 14);
    float4 v; float* vp = (float*)&v;
    for (int h = 0; h < 4; h++) {
      float s = (which == 0) ? b1[h] : 0.0f;
      for (int j = 0; j < nb; j++)
        if ((e >> j) & 1) s += W1[h * (LL + 1) + 1 + lo + j];
      vp[h] = s;
    }
    if (which == 0) tab0[e] = v; else if (which == 1) tab1[e] = v; else tab2[e] = v;
  }
  __syncthreads();
  float p = ws[OFF_PCHAIN + t];
  float a0 = W1[0], a1 = W1[LL + 1], a2 = W1[2 * (LL + 1)], a3 = W1[3 * (LL + 1)];
  float pa0 = p * a0, pa1 = p * a1, pa2 = p * a2, pa3 = p * a3;
  float w0 = W2[0], w1 = W2[1], w2 = W2[2], w3 = W2[3];
  float b2s = b2[0];
  unsigned r0 = rank0 + (unsigned)tx * KC_CPT;
  int nI = (int)C - (int)r0;
  if (nI > KC_CPT) nI = KC_CPT;
  unsigned cmb = (nI > 0) ? unrank_lds(sBN, LL, c, r0) : 0u;

  float aE = 0.0f, aW = 0.0f;
  float aQ[4] = {0, 0, 0, 0}, aWH[4] = {0, 0, 0, 0};
  float aG[LL][4];
#pragma unroll
  for (int d = 0; d < LL; d++)
#pragma unroll
    for (int h = 0; h < 4; h++) aG[d][h] = 0.0f;

#pragma unroll 1
  for (int k = 0; k < nI; k++) {
    unsigned n = cmb;
    float4 v0 = tab0[n & 127], v1 = tab1[(n >> 7) & 127], v2 = tab2[(n >> 14) & 127];
    float t0 = fast_tanh(v0.x + v1.x + v2.x + pa0);
    float t1 = fast_tanh(v0.y + v1.y + v2.y + pa1);
    float t2 = fast_tanh(v0.z + v1.z + v2.z + pa2);
    float t3 = fast_tanh(v0.w + v1.w + v2.w + pa3);
    float outv = b2s + w0 * t0 + w1 * t1 + w2 * t2 + w3 * t3;
    float e = fast_exp(outv);
    float s0 = (1.0f - t0 * t0) * w0, s1 = (1.0f - t1 * t1) * w1;
    float s2 = (1.0f - t2 * t2) * w2, s3 = (1.0f - t3 * t3) * w3;
    float q0 = outv * s0, q1 = outv * s1, q2 = outv * s2, q3 = outv * s3;
    aE += e; aW += outv;
    aQ[0] += q0; aQ[1] += q1; aQ[2] += q2; aQ[3] += q3;
    aWH[0] += outv * t0; aWH[1] += outv * t1; aWH[2] += outv * t2; aWH[3] += outv * t3;
#pragma unroll
    for (int d = 0; d < LL; d++) {
      float bd = (float)((n >> d) & 1u);
      aG[d][0] = fmaf(bd, q0, aG[d][0]);
      aG[d][1] = fmaf(bd, q1, aG[d][1]);
      aG[d][2] = fmaf(bd, q2, aG[d][2]);
      aG[d][3] = fmaf(bd, q3, aG[d][3]);
    }
    cmb = gosper(cmb);
  }

  // wave reductions + global atomics
  auto wsum = [](float v) {
    for (int m = 1; m < 64; m <<= 1) v += __shfl_xor(v, m);
    return v;
  };
  int lane = tx & 63;
  float* S = &ws[OFF_SUMS + t * SUMS_STRIDE];
  float r;
  r = wsum(aE); if (lane == 0 && r != 0.0f) atomicAdd(&S[0], r);
  r = wsum(aW); if (lane == 0 && r != 0.0f) atomicAdd(&S[1], r);
#pragma unroll
  for (int h = 0; h < 4; h++) {
    r = wsum(aQ[h]);  if (lane == 0 && r != 0.0f) atomicAdd(&S[2 + h], r);
    r = wsum(aWH[h]); if (lane == 0 && r != 0.0f) atomicAdd(&S[6 + h], r);
  }
#pragma unroll
  for (int d = 0; d < LL; d++)
#pragma unroll
    for (int h = 0; h < 4; h++) {
      r = wsum(aG[d][h]);
      if (lane == 0 && r != 0.0f) atomicAdd(&S[10 + h * 21 + d], r);
    }
}

__global__ __launch_bounds__(256, 2) void kc(
    const float* W1_2, const float* b1_2, const float* W2_2, const float* b2_2,
    const float* W1_3, const float* b1_3, const float* W2_3, const float* b2_3,
    float* ws) {
  __shared__ unsigned sBN[484];
  __shared__ float4 tab0[128], tab1[128], tab2[128];
  int b = blockIdx.x;
  if (b < NSTEP2 * KC_B2) {
    int t = b / KC_B2, sub = b % KC_B2;
    kc_work<21>(t, sub, W1_2, b1_2, W2_2, b2_2, ws, sBN, tab0, tab1, tab2);
  } else {
    int bb = b - NSTEP2 * KC_B2;
    int t = NSTEP2 + bb / KC_B3, sub = bb % KC_B3;
    kc_work<20>(t, sub, W1_3, b1_3, W2_3, b2_3, ws, sBN, tab0, tab1, tab2);
  }
}

// =================== Kernel D: finalize gradient outputs ===================
__global__ void kd(const float* W1_2, const float* b1_2, const float* W2_2, const float* b2_2,
                   const float* W1_3, const float* b1_3, const float* W2_3, const float* b2_3,
                   const float* ws, float* out) {
  __shared__ float sk_s[NSTEPS][4], hk_s[NSTEPS][4], pp_s[NSTEPS], s0i_s[NSTEPS];
  int tx = threadIdx.x;
  if (tx < NSTEPS) {
    int t = tx; int g = (t < NSTEP2) ? 0 : 1; int L = g ? L3 : L2;
    const float* W1 = g ? W1_3 : W1_2;
    const float* W2 = g ? W2_3 : W2_2;
    float p = ws[OFF_PCHAIN + t];
    pp_s[t] = p;
    s0i_s[t] = 1.0f / ws[OFF_SUMS + t * SUMS_STRIDE + 0];
    for (int h = 0; h < 4; h++) {
      float hk = fast_tanh(ws[OFF_KEYB + t * 4 + h] + p * W1[h * (L + 1)]);
      hk_s[t][h] = hk;
      sk_s[t][h] = (1.0f - hk * hk) * W2[h];
    }
  }
  __syncthreads();
  const unsigned* cbp = (const unsigned*)ws;
  for (int o = 33 + tx; o < 223; o += blockDim.x) {
    float val = 0.0f;
    if (o < 130) {                           // ---- group2 grads ----
      if (o < 121) {                         // W1_2 grad [4][22]
        int e = o - 33; int h = e / 22, d = e % 22;
        for (int t = 0; t < NSTEP2; t++) {
          float xk = (d == 0) ? pp_s[t] : (float)((cbp[OFF_CB + t] >> (d - 1)) & 1);
          float gs = (d == 0) ? pp_s[t] * ws[OFF_SUMS + t * SUMS_STRIDE + 2 + h]
                              : ws[OFF_SUMS + t * SUMS_STRIDE + 10 + h * 21 + (d - 1)];
          val += sk_s[t][h] * xk - gs * s0i_s[t];
        }
      } else if (o < 125) { int h = o - 121;
        for (int t = 0; t < NSTEP2; t++) val += sk_s[t][h] - ws[OFF_SUMS + t * SUMS_STRIDE + 2 + h] * s0i_s[t];
      } else if (o < 129) { int h = o - 125;
        for (int t = 0; t < NSTEP2; t++) val += hk_s[t][h] - ws[OFF_SUMS + t * SUMS_STRIDE + 6 + h] * s0i_s[t];
      } else {
        for (int t = 0; t < NSTEP2; t++) val += 1.0f - ws[OFF_SUMS + t * SUMS_STRIDE + 1] * s0i_s[t];
      }
    } else {                                 // ---- group3 grads ----
      if (o < 214) {                         // W1_3 grad [4][21]
        int e = o - 130; int h = e / 21, d = e % 21;
        for (int t = NSTEP2; t < NSTEPS; t++) {
          float xk = (d == 0) ? pp_s[t] : (float)((cbp[OFF_CB + t] >> (d - 1)) & 1);
          float gs = (d == 0) ? pp_s[t] * ws[OFF_SUMS + t * SUMS_STRIDE + 2 + h]
                              : ws[OFF_SUMS + t * SUMS_STRIDE + 10 + h * 21 + (d - 1)];
          val += sk_s[t][h] * xk - gs * s0i_s[t];
        }
      } else if (o < 218) { int h = o - 214;
        for (int t = NSTEP2; t < NSTEPS; t++) val += sk_s[t][h] - ws[OFF_SUMS + t * SUMS_STRIDE + 2 + h] * s0i_s[t];
      } else if (o < 222) { int h = o - 218;
        for (int t = NSTEP2; t < NSTEPS; t++) val += hk_s[t][h] - ws[OFF_SUMS + t * SUMS_STRIDE + 6 + h] * s0i_s[t];
      } else {
        for (int t = NSTEP2; t < NSTEPS; t++) val += 1.0f - ws[OFF_SUMS + t * SUMS_STRIDE + 1] * s0i_s[t];
      }
    }
    out[o] = val;
  }
}

extern "C" void kernel_launch(void* const* d_in, const int* in_sizes, int n_in,
                              void* d_out, int out_size, void* d_ws, size_t ws_size,
                              hipStream_t stream) {
  const float* p0   = (const float*)d_in[0];
  const float* sel  = (const float*)d_in[1];
  const float* W1_2 = (const float*)d_in[2]; const float* b1_2 = (const float*)d_in[3];
  const float* W2_2 = (const float*)d_in[4]; const float* b2_2 = (const float*)d_in[5];
  const float* W1_3 = (const float*)d_in[6]; const float* b1_3 = (const float*)d_in[7];
  const float* W2_3 = (const float*)d_in[8]; const float* b2_3 = (const float*)d_in[9];
  float* out = (float*)d_out;
  float* ws  = (float*)d_ws;
  hipLaunchKernelGGL(kz, dim3(1), dim3(256), 0, stream, p0, sel, W1_2, b1_2, W1_3, b1_3, ws);
  hipLaunchKernelGGL(ka, dim3(KAOFF.total), dim3(256), 0, stream,
                     W1_2, b1_2, W2_2, b2_2, W1_3, b1_3, W2_3, b2_3, ws);
  hipLaunchKernelGGL(kb, dim3(1), dim3(64), 0, stream, p0,
                     W1_2, b1_2, W2_2, b2_2, W1_3, b1_3, W2_3, b2_3, ws, out);
  hipLaunchKernelGGL(kc, dim3(KC_BLOCKS), dim3(256), 0, stream,
                     W1_2, b1_2, W2_2, b2_2, W1_3, b1_3, W2_3, b2_3, ws);
  hipLaunchKernelGGL(kd, dim3(1), dim3(256), 0, stream,
                     W1_2, b1_2, W2_2, b2_2, W1_3, b1_3, W2_3, b2_3, ws, out);
}